// Round 2
// baseline (2183.630 us; speedup 1.0000x reference)
//
#include <hip/hip_runtime.h>
#include <hip/hip_fp16.h>

#define BATCH 8192
#define FDIM  512
#define NTREE 64
#define NODES 63
#define ODIM  128
#define NJ    (NODES*NTREE)   // 4032

typedef __bf16 bf16;
typedef __bf16 bf16x8 __attribute__((ext_vector_type(8)));
typedef float  f32x4  __attribute__((ext_vector_type(4)));

// ---------------- workspace layout (bytes) ----------------
#define X_BF_OFF   0
#define X_BF_SZ    ((size_t)BATCH*FDIM*2)            // 8.39 MB  x as bf16 [b][f]
#define WN_OFF     (X_BF_OFF + X_BF_SZ)
#define WN_SZ      ((size_t)NODES*FDIM*NTREE*2)      // 4.13 MB  Wn as bf16 TRANSPOSED [n][t][f]
#define WL_OFF     (WN_OFF + WN_SZ)
#define WL_SZ      ((size_t)64*ODIM*NTREE*2)         // 1.05 MB  Wl as bf16 [l][o][t]
#define S_OFF      (WL_OFF + WL_SZ)
#define S_SZ       ((size_t)BATCH*NJ*2)              // 66.06 MB s as fp16 [b][n*64+t]
#define WS_NEEDED  (S_OFF + S_SZ)

__device__ __forceinline__ float smooth_step_f(float t) {
    float tc = fminf(fmaxf(t, -0.5f), 0.5f);
    return fmaf(tc, fmaf(-2.0f * tc, tc, 1.5f), 0.5f);
}

__device__ __forceinline__ void async16(const void* g, void* l) {
    __builtin_amdgcn_global_load_lds((__attribute__((address_space(1))) void*)g,
                                     (__attribute__((address_space(3))) void*)l,
                                     16, 0, 0);
}

// ---------------- conversion kernels ----------------
__global__ void conv_x_kernel(const float* __restrict__ in, bf16* __restrict__ out) {
    // 4,194,304 elems, float4 per thread
    size_t i = ((size_t)blockIdx.x * blockDim.x + threadIdx.x) * 4;
    float4 v = *(const float4*)(in + i);
    bf16* o = out + i;
    o[0] = (bf16)v.x; o[1] = (bf16)v.y; o[2] = (bf16)v.z; o[3] = (bf16)v.w;
}

__global__ void conv_wl_kernel(const float* __restrict__ in, bf16* __restrict__ out) {
    size_t i = ((size_t)blockIdx.x * blockDim.x + threadIdx.x) * 4;
    float4 v = *(const float4*)(in + i);
    bf16* o = out + i;
    o[0] = (bf16)v.x; o[1] = (bf16)v.y; o[2] = (bf16)v.z; o[3] = (bf16)v.w;
}

// transpose + convert: Wn[n][f][t] (fp32) -> Wn_c[n][t][f] (bf16)
__global__ void conv_wn_kernel(const float* __restrict__ wn, bf16* __restrict__ out) {
    __shared__ float tile[64][65];                 // +1 pad: conflict-free transpose
    const int n  = blockIdx.x;                     // 0..62
    const int f0 = blockIdx.y * 64;                // 8 f-tiles
    const int lane = threadIdx.x & 63;
    const int w    = threadIdx.x >> 6;
    const float* src = wn + (size_t)n * (FDIM * NTREE);
    #pragma unroll
    for (int i = 0; i < 16; ++i) {
        int fl = w * 16 + i;
        tile[fl][lane] = src[(size_t)(f0 + fl) * NTREE + lane];   // coalesced
    }
    __syncthreads();
    bf16* dst = out + (size_t)n * (NTREE * FDIM);
    #pragma unroll
    for (int i = 0; i < 16; ++i) {
        int tr = w * 16 + i;
        dst[(size_t)tr * FDIM + f0 + lane] = (bf16)tile[lane][tr]; // coalesced
    }
}

// ---------------- phase 1: bf16 MFMA GEMM + bias + smooth_step -> s (fp16) ----------------
// C[row][j] = sum_f x[row][f] * WnT[j][f],  j = n*64 + t ; block: 128 rows x 64 cols (one node)
__global__ __launch_bounds__(256, 2)
void gemm_nodes(const bf16* __restrict__ xb, const bf16* __restrict__ wnc,
                const float* __restrict__ bn, __half* __restrict__ s_out)
{
    __shared__ bf16 Asm[128 * 64];   // [m][k] 16 KB
    __shared__ bf16 Bsm[64 * 64];    // [t][k] 8 KB
    const int tid  = threadIdx.x;
    const int lane = tid & 63;
    const int w    = tid >> 6;
    const int wm   = w & 1;          // wave m-half (64 rows)
    const int wnh  = w >> 1;         // wave n-half (32 cols)
    const int n    = blockIdx.x;     // node
    const int row0 = blockIdx.y * 128;

    f32x4 acc[4][2] = {};
    const bf16* wnode = wnc + (size_t)n * (NTREE * FDIM);

    for (int k0 = 0; k0 < FDIM; k0 += 64) {
        // stage A: 16 KB = 16 chunks of 1KB (8 rows each); wave w: chunks w*4..w*4+3
        #pragma unroll
        for (int c = 0; c < 4; ++c) {
            int chunk = w * 4 + c;
            int r  = chunk * 8 + (lane >> 3);
            int kk = (lane & 7) * 8;
            async16(xb + (size_t)(row0 + r) * FDIM + k0 + kk, &Asm[chunk * 512]);
        }
        // stage B: 8 KB = 8 chunks; wave w: chunks w*2..w*2+1
        #pragma unroll
        for (int c = 0; c < 2; ++c) {
            int chunk = w * 2 + c;
            int t  = chunk * 8 + (lane >> 3);
            int kk = (lane & 7) * 8;
            async16(wnode + (size_t)t * FDIM + k0 + kk, &Bsm[chunk * 512]);
        }
        __syncthreads();
        #pragma unroll
        for (int ks = 0; ks < 2; ++ks) {
            int kb = ks * 32 + (lane >> 4) * 8;
            bf16x8 bfr[2];
            #pragma unroll
            for (int tn = 0; tn < 2; ++tn) {
                int t = wnh * 32 + tn * 16 + (lane & 15);
                bfr[tn] = *(const bf16x8*)&Bsm[t * 64 + kb];
            }
            #pragma unroll
            for (int tm = 0; tm < 4; ++tm) {
                int m = wm * 64 + tm * 16 + (lane & 15);
                bf16x8 afr = *(const bf16x8*)&Asm[m * 64 + kb];
                #pragma unroll
                for (int tn = 0; tn < 2; ++tn)
                    acc[tm][tn] = __builtin_amdgcn_mfma_f32_16x16x32_bf16(afr, bfr[tn], acc[tm][tn], 0, 0, 0);
            }
        }
        __syncthreads();
    }
    // epilogue: bias + smooth_step, store fp16
    #pragma unroll
    for (int tm = 0; tm < 4; ++tm) {
        #pragma unroll
        for (int tn = 0; tn < 2; ++tn) {
            int col = wnh * 32 + tn * 16 + (lane & 15);
            int j   = n * 64 + col;
            float bias = bn[j];
            #pragma unroll
            for (int r = 0; r < 4; ++r) {
                int row = row0 + wm * 64 + tm * 16 + (lane >> 4) * 4 + r;
                float v = acc[tm][tn][r] + bias;
                s_out[(size_t)row * NJ + j] = __float2half(smooth_step_f(v));
            }
        }
    }
}

// ---------------- phase 2: prob build + leaf contraction ----------------
__device__ __forceinline__ void build_prob_g(const __half* __restrict__ srow,
                                             int lane, float (&pr)[64]) {
    pr[0] = 1.0f;
    int base = 0;
    #pragma unroll
    for (int lvl = 0; lvl < 6; ++lvl) {
        const int width = 1 << lvl;
        float sl[32];
        #pragma unroll
        for (int i = 0; i < width; ++i)
            sl[i] = __half2float(srow[(size_t)(base + i) * NTREE + lane]);  // coalesced
        #pragma unroll
        for (int i = width - 1; i >= 0; --i) {
            float p = pr[i];
            pr[2 * i]     = p * sl[i];
            pr[2 * i + 1] = p * (1.0f - sl[i]);
        }
        base += width;
    }
}

__global__ __launch_bounds__(256, 4)
void leaf_kernel(const __half* __restrict__ s_ws, const bf16* __restrict__ wl,
                 float* __restrict__ out)
{
    const int lane = threadIdx.x & 63;    // = tree t
    const int w    = threadIdx.x >> 6;
    const long row0 = (long)blockIdx.x * 8;
    const int r0 = w * 2, r1 = w * 2 + 1;

    float pr0[64], pr1[64];
    build_prob_g(s_ws + (size_t)(row0 + r0) * NJ, lane, pr0);
    build_prob_g(s_ws + (size_t)(row0 + r1) * NJ, lane, pr1);

    for (int o = 0; o < ODIM; ++o) {
        const bf16* wlp = wl + (size_t)o * NTREE + lane;   // Wl[l][o][lane]
        float c0 = 0.0f, c1 = 0.0f;
        #pragma unroll
        for (int l = 0; l < 64; ++l) {
            float wv = (float)wlp[(size_t)l * (ODIM * NTREE)];  // coalesced
            c0 = fmaf(pr0[l], wv, c0);
            c1 = fmaf(pr1[l], wv, c1);
        }
        #pragma unroll
        for (int off = 32; off > 0; off >>= 1) {
            c0 += __shfl_xor(c0, off, 64);
            c1 += __shfl_xor(c1, off, 64);
        }
        if (lane == 0) {
            out[(row0 + r0) * ODIM + o] = c0;
            out[(row0 + r1) * ODIM + o] = c1;
        }
    }
}

// ---------------- fallback (round-1 proven kernel) if ws too small ----------------
#define ROWS 8
__global__ __launch_bounds__(256, 2)
void soft_tree_fallback(const float* __restrict__ x, const float* __restrict__ Wn,
                        const float* __restrict__ bn, const float* __restrict__ Wl,
                        float* __restrict__ out)
{
    __shared__ __half s_lds[ROWS][NODES][NTREE];
    const int lane = threadIdx.x & 63;
    const int w    = threadIdx.x >> 6;
    const long row0 = (long)blockIdx.x * ROWS;
    for (int n = w; n < NODES; n += 4) {
        const float* wp = Wn + ((long)n * FDIM) * NTREE + lane;
        const float* xp = x + row0 * FDIM;
        float acc[ROWS];
        #pragma unroll
        for (int r = 0; r < ROWS; ++r) acc[r] = 0.0f;
        #pragma unroll 8
        for (int f = 0; f < FDIM; ++f) {
            float wv = wp[(long)f * NTREE];
            #pragma unroll
            for (int r = 0; r < ROWS; ++r)
                acc[r] = fmaf(xp[r * FDIM + f], wv, acc[r]);
        }
        float bias = bn[n * NTREE + lane];
        #pragma unroll
        for (int r = 0; r < ROWS; ++r)
            s_lds[r][n][lane] = __float2half(smooth_step_f(acc[r] + bias));
    }
    __syncthreads();
    const int r0 = w * 2, r1 = w * 2 + 1;
    float pr0[64], pr1[64];
    {
        pr0[0] = 1.0f; pr1[0] = 1.0f;
        int base = 0;
        #pragma unroll
        for (int lvl = 0; lvl < 6; ++lvl) {
            const int width = 1 << lvl;
            #pragma unroll
            for (int i = width - 1; i >= 0; --i) {
                float sa = __half2float(s_lds[r0][base + i][lane]);
                float sb = __half2float(s_lds[r1][base + i][lane]);
                float pa = pr0[i], pb = pr1[i];
                pr0[2 * i] = pa * sa; pr0[2 * i + 1] = pa * (1.0f - sa);
                pr1[2 * i] = pb * sb; pr1[2 * i + 1] = pb * (1.0f - sb);
            }
            base += width;
        }
    }
    for (int o = 0; o < ODIM; ++o) {
        const float* wlp = Wl + (long)o * NTREE + lane;
        float c0 = 0.0f, c1 = 0.0f;
        #pragma unroll
        for (int l = 0; l < 64; ++l) {
            float wv = wlp[(long)l * (ODIM * NTREE)];
            c0 = fmaf(pr0[l], wv, c0);
            c1 = fmaf(pr1[l], wv, c1);
        }
        #pragma unroll
        for (int off = 32; off > 0; off >>= 1) {
            c0 += __shfl_xor(c0, off, 64);
            c1 += __shfl_xor(c1, off, 64);
        }
        if (lane == 0) {
            out[(row0 + r0) * ODIM + o] = c0;
            out[(row0 + r1) * ODIM + o] = c1;
        }
    }
}

extern "C" void kernel_launch(void* const* d_in, const int* in_sizes, int n_in,
                              void* d_out, int out_size, void* d_ws, size_t ws_size,
                              hipStream_t stream) {
    const float* x  = (const float*)d_in[0];
    const float* Wn = (const float*)d_in[1];
    const float* bn = (const float*)d_in[2];
    const float* Wl = (const float*)d_in[3];
    float* out = (float*)d_out;

    if (ws_size < WS_NEEDED) {
        soft_tree_fallback<<<BATCH / ROWS, 256, 0, stream>>>(x, Wn, bn, Wl, out);
        return;
    }

    bf16*   xb  = (bf16*)((char*)d_ws + X_BF_OFF);
    bf16*   wnc = (bf16*)((char*)d_ws + WN_OFF);
    bf16*   wlb = (bf16*)((char*)d_ws + WL_OFF);
    __half* sws = (__half*)((char*)d_ws + S_OFF);

    conv_x_kernel <<<(BATCH * FDIM) / (256 * 4), 256, 0, stream>>>(x, xb);      // 4096 blocks
    conv_wl_kernel<<<(64 * ODIM * NTREE) / (256 * 4), 256, 0, stream>>>(Wl, wlb); // 512 blocks
    conv_wn_kernel<<<dim3(NODES, FDIM / 64), 256, 0, stream>>>(Wn, wnc);        // 63x8 blocks

    gemm_nodes<<<dim3(NODES, BATCH / 128), 256, 0, stream>>>(xb, wnc, bn, sws); // 63x64 blocks
    leaf_kernel<<<BATCH / 8, 256, 0, stream>>>(sws, wlb, out);                  // 1024 blocks
}

// Round 3
// 201.736 us; speedup vs baseline: 10.8242x; 10.8242x over previous
//
#include <hip/hip_runtime.h>
#include <hip/hip_fp16.h>

#define BATCH 8192
#define FDIM  512
#define NTREE 64
#define NODES 63
#define ODIM  128
#define NJ    (NODES*NTREE)   // 4032 real node-tree columns
#define NJP   4096            // padded
#define K2    4096            // leaf GEMM K = 64 leaves * 64 trees

typedef _Float16 f16;
typedef _Float16 f16x8 __attribute__((ext_vector_type(8)));
typedef float    f32x4 __attribute__((ext_vector_type(4)));

// ---------------- workspace layout (bytes) ----------------
#define XH_OFF   0
#define XH_SZ    ((size_t)BATCH*FDIM*2)        // 8.39 MB  x  f16 [b][f]
#define WNH_OFF  (XH_OFF + XH_SZ)
#define WNH_SZ   ((size_t)NJP*FDIM*2)          // 4.19 MB  Wn f16 [j=n*64+t][f], pad j zeroed
#define WLT_OFF  (WNH_OFF + WNH_SZ)
#define WLT_SZ   ((size_t)ODIM*K2*2)           // 1.05 MB  Wl f16 [o][l*64+t]
#define SP_OFF   (WLT_OFF + WLT_SZ)
#define SP_SZ    ((size_t)BATCH*NJP*2)         // 67.1 MB  s f16 [b][j] -> prob f16 [b][k] in place
#define WS_NEEDED (SP_OFF + SP_SZ)

__device__ __forceinline__ float smooth_step_f(float t) {
    float tc = fminf(fmaxf(t, -0.5f), 0.5f);
    return fmaf(tc, fmaf(-2.0f * tc, tc, 1.5f), 0.5f);
}

__device__ __forceinline__ void async16(const void* g, void* l) {
    __builtin_amdgcn_global_load_lds((__attribute__((address_space(1))) void*)g,
                                     (__attribute__((address_space(3))) void*)l,
                                     16, 0, 0);
}

// ---------------- conversions ----------------
__global__ void conv_x_kernel(const float* __restrict__ in, f16* __restrict__ out) {
    size_t i = ((size_t)blockIdx.x * blockDim.x + threadIdx.x) * 4;
    float4 v = *(const float4*)(in + i);
    f16* o = out + i;
    o[0] = (f16)v.x; o[1] = (f16)v.y; o[2] = (f16)v.z; o[3] = (f16)v.w;
}

// Wl[l][o][t] fp32 -> Wlt[o][l*64+t] f16
__global__ void conv_wl_kernel(const float* __restrict__ in, f16* __restrict__ out) {
    const int l    = blockIdx.x;          // 0..63
    const int os   = threadIdx.x >> 6;    // 0..3
    const int t    = threadIdx.x & 63;
    for (int oo = 0; oo < 32; ++oo) {
        int o = oo * 4 + os;
        out[(size_t)o * K2 + l * 64 + t] = (f16)in[(size_t)l * (ODIM * NTREE) + o * 64 + t];
    }
}

// Wn[n][f][t] fp32 -> Wnh[(n*64+t)][f] f16 ; block n==63 zeros the pad rows
__global__ void conv_wn_kernel(const float* __restrict__ wn, f16* __restrict__ out) {
    const int n    = blockIdx.x;          // 0..63 (63 = pad)
    const int f0   = blockIdx.y * 64;
    const int lane = threadIdx.x & 63;
    const int w    = threadIdx.x >> 6;
    if (n == NODES) {
        #pragma unroll
        for (int jj = 0; jj < 16; ++jj) {
            int j = NJ + w * 16 + jj;
            out[(size_t)j * FDIM + f0 + lane] = (f16)0.0f;
        }
        return;
    }
    __shared__ float tile[64][65];
    const float* src = wn + (size_t)n * (FDIM * NTREE);
    #pragma unroll
    for (int i = 0; i < 16; ++i) {
        int fl = w * 16 + i;
        tile[fl][lane] = src[(size_t)(f0 + fl) * NTREE + lane];
    }
    __syncthreads();
    #pragma unroll
    for (int i = 0; i < 16; ++i) {
        int tr = w * 16 + i;
        out[(size_t)(n * 64 + tr) * FDIM + f0 + lane] = (f16)tile[lane][tr];
    }
}

// ---------------- phase 1: node GEMM (M=8192, N=4096pad, K=512) + bias + smooth_step ----------------
__global__ __launch_bounds__(256, 2)
void gemm_nodes(const f16* __restrict__ xh, const f16* __restrict__ wnh,
                const float* __restrict__ bn, f16* __restrict__ s_out)
{
    __shared__ f16 Ash[128 * 64];   // 16 KB [m][k]
    __shared__ f16 Bsh[128 * 64];   // 16 KB [j][k]
    const int tid  = threadIdx.x;
    const int lane = tid & 63;
    const int w    = tid >> 6;
    const int wm   = w & 1;
    const int wn   = w >> 1;
    const int j0   = blockIdx.x * 128;
    const int row0 = blockIdx.y * 128;

    f32x4 acc[4][4] = {};

    for (int k0 = 0; k0 < FDIM; k0 += 64) {
        #pragma unroll
        for (int c = 0; c < 4; ++c) {
            int chunk = w * 4 + c;
            int r  = chunk * 8 + (lane >> 3);
            int kk = (lane & 7) * 8;
            async16(xh + (size_t)(row0 + r) * FDIM + k0 + kk, &Ash[chunk * 512]);
            async16(wnh + (size_t)(j0 + r) * FDIM + k0 + kk, &Bsh[chunk * 512]);
        }
        __syncthreads();
        #pragma unroll
        for (int ks = 0; ks < 2; ++ks) {
            int kb = ks * 32 + (lane >> 4) * 8;
            f16x8 bfr[4];
            #pragma unroll
            for (int tn = 0; tn < 4; ++tn) {
                int j = wn * 64 + tn * 16 + (lane & 15);
                bfr[tn] = *(const f16x8*)&Bsh[j * 64 + kb];
            }
            #pragma unroll
            for (int tm = 0; tm < 4; ++tm) {
                int m = wm * 64 + tm * 16 + (lane & 15);
                f16x8 afr = *(const f16x8*)&Ash[m * 64 + kb];
                #pragma unroll
                for (int tn = 0; tn < 4; ++tn)
                    acc[tm][tn] = __builtin_amdgcn_mfma_f32_16x16x32_f16(afr, bfr[tn], acc[tm][tn], 0, 0, 0);
            }
        }
        __syncthreads();
    }
    #pragma unroll
    for (int tn = 0; tn < 4; ++tn) {
        int j = j0 + wn * 64 + tn * 16 + (lane & 15);
        if (j < NJ) {
            float bias = bn[j];
            #pragma unroll
            for (int tm = 0; tm < 4; ++tm) {
                #pragma unroll
                for (int r = 0; r < 4; ++r) {
                    int row = row0 + wm * 64 + tm * 16 + (lane >> 4) * 4 + r;
                    float v = acc[tm][tn][r] + bias;
                    s_out[(size_t)row * NJP + j] = (f16)smooth_step_f(v);
                }
            }
        }
    }
}

// ---------------- phase 2: prob build, IN PLACE over s row ----------------
__global__ __launch_bounds__(256, 4)
void prob_kernel(f16* sp)
{
    __shared__ f16 stage[4][K2];   // 32 KB, wave-private rows
    const int lane = threadIdx.x & 63;   // tree t
    const int w    = threadIdx.x >> 6;
    const size_t row = (size_t)blockIdx.x * 4 + w;
    f16* rp = sp + row * NJP;

    float pr[32];
    pr[0] = 1.0f;
    int base = 0;
    #pragma unroll
    for (int lvl = 0; lvl < 5; ++lvl) {
        const int width = 1 << lvl;
        float sl[16];
        #pragma unroll
        for (int i = 0; i < width; ++i)
            sl[i] = (float)rp[(size_t)(base + i) * 64 + lane];
        #pragma unroll
        for (int i = width - 1; i >= 0; --i) {
            float p = pr[i];
            pr[2 * i]     = p * sl[i];
            pr[2 * i + 1] = p * (1.0f - sl[i]);
        }
        base += width;
    }
    // level 5: read remaining 32 gates BEFORE any write (in-place safety)
    float s5[32];
    #pragma unroll
    for (int i = 0; i < 32; ++i)
        s5[i] = (float)rp[(size_t)(31 + i) * 64 + lane];
    #pragma unroll
    for (int i = 0; i < 32; ++i) {
        float p = pr[i];
        stage[w][(2 * i) * 64 + lane]     = (f16)(p * s5[i]);
        stage[w][(2 * i + 1) * 64 + lane] = (f16)(p * (1.0f - s5[i]));
    }
    // vector copy LDS -> global (overwrites the s row with prob)
    const int4* sstage = (const int4*)stage[w];
    int4* drow = (int4*)rp;
    #pragma unroll
    for (int c = 0; c < 8; ++c)
        drow[c * 64 + lane] = sstage[c * 64 + lane];
}

// ---------------- phase 3: leaf GEMM (M=8192, N=128, K=4096) ----------------
__global__ __launch_bounds__(256, 2)
void leaf_gemm(const f16* __restrict__ prob, const f16* __restrict__ wlt,
               float* __restrict__ out)
{
    __shared__ f16 Ash[32 * 64];    // 4 KB  [m][k]
    __shared__ f16 Bsh[128 * 64];   // 16 KB [o][k]
    const int tid  = threadIdx.x;
    const int lane = tid & 63;
    const int w    = tid >> 6;
    const int wm   = w & 1;
    const int wn   = w >> 1;
    const int row0 = blockIdx.x * 32;

    f32x4 acc[4] = {};

    for (int k0 = 0; k0 < K2; k0 += 64) {
        {   // A: 4 chunks of 8 rows, one per wave
            int r  = w * 8 + (lane >> 3);
            int kk = (lane & 7) * 8;
            async16(prob + (size_t)(row0 + r) * NJP + k0 + kk, &Ash[w * 512]);
        }
        #pragma unroll
        for (int c = 0; c < 4; ++c) {   // B: 16 chunks
            int chunk = w * 4 + c;
            int o  = chunk * 8 + (lane >> 3);
            int kk = (lane & 7) * 8;
            async16(wlt + (size_t)o * K2 + k0 + kk, &Bsh[chunk * 512]);
        }
        __syncthreads();
        #pragma unroll
        for (int ks = 0; ks < 2; ++ks) {
            int kb = ks * 32 + (lane >> 4) * 8;
            int m  = wm * 16 + (lane & 15);
            f16x8 afr = *(const f16x8*)&Ash[m * 64 + kb];
            #pragma unroll
            for (int tn = 0; tn < 4; ++tn) {
                int o = wn * 64 + tn * 16 + (lane & 15);
                f16x8 bfr = *(const f16x8*)&Bsh[o * 64 + kb];
                acc[tn] = __builtin_amdgcn_mfma_f32_16x16x32_f16(afr, bfr, acc[tn], 0, 0, 0);
            }
        }
        __syncthreads();
    }
    #pragma unroll
    for (int tn = 0; tn < 4; ++tn) {
        int o = wn * 64 + tn * 16 + (lane & 15);
        #pragma unroll
        for (int r = 0; r < 4; ++r) {
            int row = row0 + wm * 16 + (lane >> 4) * 4 + r;
            out[(size_t)row * ODIM + o] = acc[tn][r];
        }
    }
}

// ---------------- fallback (round-1 proven kernel) ----------------
#define ROWS 8
__global__ __launch_bounds__(256, 2)
void soft_tree_fallback(const float* __restrict__ x, const float* __restrict__ Wn,
                        const float* __restrict__ bn, const float* __restrict__ Wl,
                        float* __restrict__ out)
{
    __shared__ __half s_lds[ROWS][NODES][NTREE];
    const int lane = threadIdx.x & 63;
    const int w    = threadIdx.x >> 6;
    const long row0 = (long)blockIdx.x * ROWS;
    for (int n = w; n < NODES; n += 4) {
        const float* wp = Wn + ((long)n * FDIM) * NTREE + lane;
        const float* xp = x + row0 * FDIM;
        float acc[ROWS];
        #pragma unroll
        for (int r = 0; r < ROWS; ++r) acc[r] = 0.0f;
        #pragma unroll 8
        for (int f = 0; f < FDIM; ++f) {
            float wv = wp[(long)f * NTREE];
            #pragma unroll
            for (int r = 0; r < ROWS; ++r)
                acc[r] = fmaf(xp[r * FDIM + f], wv, acc[r]);
        }
        float bias = bn[n * NTREE + lane];
        #pragma unroll
        for (int r = 0; r < ROWS; ++r)
            s_lds[r][n][lane] = __float2half(smooth_step_f(acc[r] + bias));
    }
    __syncthreads();
    const int r0 = w * 2, r1 = w * 2 + 1;
    float pr0[64], pr1[64];
    {
        pr0[0] = 1.0f; pr1[0] = 1.0f;
        int base = 0;
        #pragma unroll
        for (int lvl = 0; lvl < 6; ++lvl) {
            const int width = 1 << lvl;
            #pragma unroll
            for (int i = width - 1; i >= 0; --i) {
                float sa = __half2float(s_lds[r0][base + i][lane]);
                float sb = __half2float(s_lds[r1][base + i][lane]);
                float pa = pr0[i], pb = pr1[i];
                pr0[2 * i] = pa * sa; pr0[2 * i + 1] = pa * (1.0f - sa);
                pr1[2 * i] = pb * sb; pr1[2 * i + 1] = pb * (1.0f - sb);
            }
            base += width;
        }
    }
    for (int o = 0; o < ODIM; ++o) {
        const float* wlp = Wl + (long)o * NTREE + lane;
        float c0 = 0.0f, c1 = 0.0f;
        #pragma unroll
        for (int l = 0; l < 64; ++l) {
            float wv = wlp[(long)l * (ODIM * NTREE)];
            c0 = fmaf(pr0[l], wv, c0);
            c1 = fmaf(pr1[l], wv, c1);
        }
        #pragma unroll
        for (int off = 32; off > 0; off >>= 1) {
            c0 += __shfl_xor(c0, off, 64);
            c1 += __shfl_xor(c1, off, 64);
        }
        if (lane == 0) {
            out[(row0 + r0) * ODIM + o] = c0;
            out[(row0 + r1) * ODIM + o] = c1;
        }
    }
}

extern "C" void kernel_launch(void* const* d_in, const int* in_sizes, int n_in,
                              void* d_out, int out_size, void* d_ws, size_t ws_size,
                              hipStream_t stream) {
    const float* x  = (const float*)d_in[0];
    const float* Wn = (const float*)d_in[1];
    const float* bn = (const float*)d_in[2];
    const float* Wl = (const float*)d_in[3];
    float* out = (float*)d_out;

    if (ws_size < WS_NEEDED) {
        soft_tree_fallback<<<BATCH / ROWS, 256, 0, stream>>>(x, Wn, bn, Wl, out);
        return;
    }

    f16* xh  = (f16*)((char*)d_ws + XH_OFF);
    f16* wnh = (f16*)((char*)d_ws + WNH_OFF);
    f16* wlt = (f16*)((char*)d_ws + WLT_OFF);
    f16* sp  = (f16*)((char*)d_ws + SP_OFF);

    conv_x_kernel <<<(BATCH * FDIM) / (256 * 4), 256, 0, stream>>>(x, xh);
    conv_wl_kernel<<<64, 256, 0, stream>>>(Wl, wlt);
    conv_wn_kernel<<<dim3(64, FDIM / 64), 256, 0, stream>>>(Wn, wnh);

    gemm_nodes<<<dim3(NJP / 128, BATCH / 128), 256, 0, stream>>>(xh, wnh, bn, sp);
    prob_kernel<<<BATCH / 4, 256, 0, stream>>>(sp);
    leaf_gemm<<<BATCH / 32, 256, 0, stream>>>(sp, wlt, out);
}

// Round 4
// 179.214 us; speedup vs baseline: 12.1844x; 1.1257x over previous
//
#include <hip/hip_runtime.h>
#include <hip/hip_fp16.h>

#define BATCH 8192
#define FDIM  512
#define NTREE 64
#define NODES 63
#define ODIM  128
#define NJ    (NODES*NTREE)   // 4032 real node-tree columns
#define NJP   4096            // padded
#define K2    4096            // leaf GEMM K = 64 leaves * 64 trees

typedef _Float16 f16;
typedef _Float16 f16x8 __attribute__((ext_vector_type(8)));
typedef float    f32x4 __attribute__((ext_vector_type(4)));

// ---------------- workspace layout (bytes) ----------------
#define XH_OFF   0
#define XH_SZ    ((size_t)BATCH*FDIM*2)        // 8.39 MB  x  f16 [b][f]
#define WNH_OFF  (XH_OFF + XH_SZ)
#define WNH_SZ   ((size_t)NJP*FDIM*2)          // 4.19 MB  Wn f16 [j=n*64+t][f], pad j zeroed
#define WLT_OFF  (WNH_OFF + WNH_SZ)
#define WLT_SZ   ((size_t)ODIM*K2*2)           // 1.05 MB  Wl f16 [o][l*64+t]
#define SP_OFF   (WLT_OFF + WLT_SZ)
#define SP_SZ    ((size_t)BATCH*NJP*2)         // 67.1 MB  s f16 [b][j] -> prob in place
#define WS_NEEDED (SP_OFF + SP_SZ)

__device__ __forceinline__ float smooth_step_f(float t) {
    float tc = fminf(fmaxf(t, -0.5f), 0.5f);
    return fmaf(tc, fmaf(-2.0f * tc, tc, 1.5f), 0.5f);
}

__device__ __forceinline__ void async16(const void* g, void* l) {
    __builtin_amdgcn_global_load_lds((__attribute__((address_space(1))) void*)g,
                                     (__attribute__((address_space(3))) void*)l,
                                     16, 0, 0);
}

// swizzled f16 offset of (row, group g) inside a [rows][64] tile staged as
// 1KB chunks of 8 rows; element (r,g) lives at chunk(r>>3), slot (r&7)*8+(g^(r&7))
__device__ __forceinline__ int sw_off(int row, int g) {
    return ((row >> 3) * 512) + (((row & 7) * 8 + (g ^ (row & 7))) * 8);
}

// ---------------- conversions ----------------
__global__ void conv_x_kernel(const float* __restrict__ in, f16* __restrict__ out) {
    size_t i = ((size_t)blockIdx.x * blockDim.x + threadIdx.x) * 4;
    float4 v = *(const float4*)(in + i);
    f16* o = out + i;
    o[0] = (f16)v.x; o[1] = (f16)v.y; o[2] = (f16)v.z; o[3] = (f16)v.w;
}

// Wl[l][o][t] fp32 -> Wlt[o][l*64+t] f16
__global__ void conv_wl_kernel(const float* __restrict__ in, f16* __restrict__ out) {
    const int l  = blockIdx.x;          // 0..63
    const int os = threadIdx.x >> 6;    // 0..3
    const int t  = threadIdx.x & 63;
    for (int oo = 0; oo < 32; ++oo) {
        int o = oo * 4 + os;
        out[(size_t)o * K2 + l * 64 + t] = (f16)in[(size_t)l * (ODIM * NTREE) + o * 64 + t];
    }
}

// Wn[n][f][t] fp32 -> Wnh[(n*64+t)][f] f16 ; block n==63 zeros the pad rows
__global__ void conv_wn_kernel(const float* __restrict__ wn, f16* __restrict__ out) {
    const int n    = blockIdx.x;          // 0..63 (63 = pad)
    const int f0   = blockIdx.y * 64;
    const int lane = threadIdx.x & 63;
    const int w    = threadIdx.x >> 6;
    if (n == NODES) {
        #pragma unroll
        for (int jj = 0; jj < 16; ++jj) {
            int j = NJ + w * 16 + jj;
            out[(size_t)j * FDIM + f0 + lane] = (f16)0.0f;
        }
        return;
    }
    __shared__ float tile[64][65];
    const float* src = wn + (size_t)n * (FDIM * NTREE);
    #pragma unroll
    for (int i = 0; i < 16; ++i) {
        int fl = w * 16 + i;
        tile[fl][lane] = src[(size_t)(f0 + fl) * NTREE + lane];
    }
    __syncthreads();
    #pragma unroll
    for (int i = 0; i < 16; ++i) {
        int tr = w * 16 + i;
        out[(size_t)(n * 64 + tr) * FDIM + f0 + lane] = (f16)tile[lane][tr];
    }
}

// ---------------- phase 1: node GEMM (M=8192, N=4096pad, K=512) + bias + smooth_step ----------------
__global__ __launch_bounds__(256, 3)
void gemm_nodes(const f16* __restrict__ xh, const f16* __restrict__ wnh,
                const float* __restrict__ bn, f16* __restrict__ s_out)
{
    __shared__ f16 Ash[128 * 64];   // 16 KB [m][k], swizzled
    __shared__ f16 Bsh[128 * 64];   // 16 KB [j][k], swizzled
    const int tid  = threadIdx.x;
    const int lane = tid & 63;
    const int w    = tid >> 6;
    const int wm   = w & 1;
    const int wn   = w >> 1;
    const int j0   = blockIdx.x * 128;
    const int row0 = blockIdx.y * 128;

    const int lr = lane >> 3;             // row-in-chunk
    const int lg = (lane & 7) ^ lr;       // swizzled group this lane fetches
    f32x4 acc[4][4] = {};

    for (int k0 = 0; k0 < FDIM; k0 += 64) {
        #pragma unroll
        for (int q = 0; q < 8; ++q) {
            int id = w * 8 + q;           // 0..31: 16 A chunks then 16 B chunks
            if (id < 16) {
                int r = id * 8 + lr;
                async16(xh + (size_t)(row0 + r) * FDIM + k0 + lg * 8, &Ash[id * 512 + lane * 8]);
            } else {
                int c = id - 16;
                int r = c * 8 + lr;
                async16(wnh + (size_t)(j0 + r) * FDIM + k0 + lg * 8, &Bsh[c * 512 + lane * 8]);
            }
        }
        __syncthreads();
        #pragma unroll
        for (int ks = 0; ks < 2; ++ks) {
            int g = ks * 4 + (lane >> 4);
            f16x8 bfr[4];
            #pragma unroll
            for (int tn = 0; tn < 4; ++tn) {
                int j = wn * 64 + tn * 16 + (lane & 15);
                bfr[tn] = *(const f16x8*)&Bsh[sw_off(j, g)];
            }
            #pragma unroll
            for (int tm = 0; tm < 4; ++tm) {
                int m = wm * 64 + tm * 16 + (lane & 15);
                f16x8 afr = *(const f16x8*)&Ash[sw_off(m, g)];
                #pragma unroll
                for (int tn = 0; tn < 4; ++tn)
                    acc[tm][tn] = __builtin_amdgcn_mfma_f32_16x16x32_f16(afr, bfr[tn], acc[tm][tn], 0, 0, 0);
            }
        }
        __syncthreads();
    }
    #pragma unroll
    for (int tn = 0; tn < 4; ++tn) {
        int j = j0 + wn * 64 + tn * 16 + (lane & 15);
        if (j < NJ) {
            float bias = bn[j];
            #pragma unroll
            for (int tm = 0; tm < 4; ++tm) {
                #pragma unroll
                for (int r = 0; r < 4; ++r) {
                    int row = row0 + wm * 64 + tm * 16 + (lane >> 4) * 4 + r;
                    float v = acc[tm][tn][r] + bias;
                    s_out[(size_t)row * NJP + j] = (f16)smooth_step_f(v);
                }
            }
        }
    }
}

// ---------------- phase 2: prob build, in place, LDS-staged ----------------
__global__ __launch_bounds__(256, 4)
void prob_kernel(f16* sp)
{
    __shared__ f16 stage[4 * 4096];      // 32 KB, one 8 KB row per wave
    const int lane = threadIdx.x & 63;   // tree t
    const int w    = threadIdx.x >> 6;
    const size_t row = (size_t)blockIdx.x * 4 + w;
    f16* rp = sp + row * NJP;
    f16* L  = stage + w * 4096;

    #pragma unroll
    for (int c = 0; c < 8; ++c)
        async16(rp + c * 512 + lane * 8, L + c * 512 + lane * 8);
    __syncthreads();   // drains vmcnt (global_load_lds complete)

    float pr[32];
    pr[0] = 1.0f;
    int base = 0;
    #pragma unroll
    for (int lvl = 0; lvl < 5; ++lvl) {
        const int width = 1 << lvl;
        float sl[16];
        #pragma unroll
        for (int i = 0; i < width; ++i)
            sl[i] = (float)L[(base + i) * 64 + lane];
        #pragma unroll
        for (int i = width - 1; i >= 0; --i) {
            float p = pr[i];
            pr[2 * i]     = p * sl[i];
            pr[2 * i + 1] = p * (1.0f - sl[i]);
        }
        base += width;
    }
    // level 5 fold, in place: step i reads gate pos 31+i BEFORE writing leaves 2i, 2i+1.
    // Future reads (31+i') never touch written positions for i<31; last step writes 62,63.
    #pragma unroll
    for (int i = 0; i < 32; ++i) {
        float s5 = (float)L[(31 + i) * 64 + lane];
        float p  = pr[i];
        L[(2 * i) * 64 + lane]     = (f16)(p * s5);
        L[(2 * i + 1) * 64 + lane] = (f16)(p * (1.0f - s5));
    }
    // vector copy LDS row -> global (overwrites s row incl. pad with prob)
    const int4* ls = (const int4*)L;
    int4* gd = (int4*)rp;
    #pragma unroll
    for (int c = 0; c < 8; ++c)
        gd[c * 64 + lane] = ls[c * 64 + lane];
}

// ---------------- phase 3: leaf GEMM (M=8192, N=128, K=4096), 16 rows/block ----------------
__global__ __launch_bounds__(256, 2)
void leaf_gemm(const f16* __restrict__ prob, const f16* __restrict__ wlt,
               float* __restrict__ out)
{
    __shared__ f16 Ash[2 * 16 * 64];    // 4 KB: 2 k-tiles of [16][64], swizzled
    __shared__ f16 Bsh[2 * 128 * 64];   // 32 KB: 2 k-tiles of [128][64], swizzled
    const int tid  = threadIdx.x;
    const int lane = tid & 63;
    const int w    = tid >> 6;
    const int row0 = blockIdx.x * 16;

    const int lr = lane >> 3;
    const int lg = (lane & 7) ^ lr;
    f32x4 acc[2] = {};

    for (int k0 = 0; k0 < K2; k0 += 128) {
        #pragma unroll
        for (int q = 0; q < 9; ++q) {
            int id = w * 9 + q;            // 0..35: 4 A chunks then 32 B chunks
            if (id < 4) {
                int t = id >> 1, c = id & 1;
                int r = c * 8 + lr;
                async16(prob + (size_t)(row0 + r) * NJP + k0 + t * 64 + lg * 8,
                        &Ash[t * 1024 + c * 512 + lane * 8]);
            } else {
                int e = id - 4;
                int t = e >> 4, c = e & 15;
                int o = c * 8 + lr;
                async16(wlt + (size_t)o * K2 + k0 + t * 64 + lg * 8,
                        &Bsh[t * 8192 + c * 512 + lane * 8]);
            }
        }
        __syncthreads();
        #pragma unroll
        for (int ks = 0; ks < 4; ++ks) {
            int t = ks >> 1;
            int g = (ks & 1) * 4 + (lane >> 4);
            int m = lane & 15;
            f16x8 afr = *(const f16x8*)&Ash[t * 1024 + sw_off(m, g)];
            #pragma unroll
            for (int tn = 0; tn < 2; ++tn) {
                int o = w * 32 + tn * 16 + (lane & 15);
                f16x8 bfr = *(const f16x8*)&Bsh[t * 8192 + sw_off(o, g)];
                acc[tn] = __builtin_amdgcn_mfma_f32_16x16x32_f16(afr, bfr, acc[tn], 0, 0, 0);
            }
        }
        __syncthreads();
    }
    #pragma unroll
    for (int tn = 0; tn < 2; ++tn) {
        int o = w * 32 + tn * 16 + (lane & 15);
        #pragma unroll
        for (int r = 0; r < 4; ++r) {
            int row = row0 + (lane >> 4) * 4 + r;
            out[(size_t)row * ODIM + o] = acc[tn][r];
        }
    }
}

// ---------------- fallback (round-1 proven kernel) ----------------
#define ROWS 8
__global__ __launch_bounds__(256, 2)
void soft_tree_fallback(const float* __restrict__ x, const float* __restrict__ Wn,
                        const float* __restrict__ bn, const float* __restrict__ Wl,
                        float* __restrict__ out)
{
    __shared__ __half s_lds[ROWS][NODES][NTREE];
    const int lane = threadIdx.x & 63;
    const int w    = threadIdx.x >> 6;
    const long row0 = (long)blockIdx.x * ROWS;
    for (int n = w; n < NODES; n += 4) {
        const float* wp = Wn + ((long)n * FDIM) * NTREE + lane;
        const float* xp = x + row0 * FDIM;
        float acc[ROWS];
        #pragma unroll
        for (int r = 0; r < ROWS; ++r) acc[r] = 0.0f;
        #pragma unroll 8
        for (int f = 0; f < FDIM; ++f) {
            float wv = wp[(long)f * NTREE];
            #pragma unroll
            for (int r = 0; r < ROWS; ++r)
                acc[r] = fmaf(xp[r * FDIM + f], wv, acc[r]);
        }
        float bias = bn[n * NTREE + lane];
        #pragma unroll
        for (int r = 0; r < ROWS; ++r)
            s_lds[r][n][lane] = __float2half(smooth_step_f(acc[r] + bias));
    }
    __syncthreads();
    const int r0 = w * 2, r1 = w * 2 + 1;
    float pr0[64], pr1[64];
    {
        pr0[0] = 1.0f; pr1[0] = 1.0f;
        int base = 0;
        #pragma unroll
        for (int lvl = 0; lvl < 6; ++lvl) {
            const int width = 1 << lvl;
            #pragma unroll
            for (int i = width - 1; i >= 0; --i) {
                float sa = __half2float(s_lds[r0][base + i][lane]);
                float sb = __half2float(s_lds[r1][base + i][lane]);
                float pa = pr0[i], pb = pr1[i];
                pr0[2 * i] = pa * sa; pr0[2 * i + 1] = pa * (1.0f - sa);
                pr1[2 * i] = pb * sb; pr1[2 * i + 1] = pb * (1.0f - sb);
            }
            base += width;
        }
    }
    for (int o = 0; o < ODIM; ++o) {
        const float* wlp = Wl + (long)o * NTREE + lane;
        float c0 = 0.0f, c1 = 0.0f;
        #pragma unroll
        for (int l = 0; l < 64; ++l) {
            float wv = wlp[(long)l * (ODIM * NTREE)];
            c0 = fmaf(pr0[l], wv, c0);
            c1 = fmaf(pr1[l], wv, c1);
        }
        #pragma unroll
        for (int off = 32; off > 0; off >>= 1) {
            c0 += __shfl_xor(c0, off, 64);
            c1 += __shfl_xor(c1, off, 64);
        }
        if (lane == 0) {
            out[(row0 + r0) * ODIM + o] = c0;
            out[(row0 + r1) * ODIM + o] = c1;
        }
    }
}

extern "C" void kernel_launch(void* const* d_in, const int* in_sizes, int n_in,
                              void* d_out, int out_size, void* d_ws, size_t ws_size,
                              hipStream_t stream) {
    const float* x  = (const float*)d_in[0];
    const float* Wn = (const float*)d_in[1];
    const float* bn = (const float*)d_in[2];
    const float* Wl = (const float*)d_in[3];
    float* out = (float*)d_out;

    if (ws_size < WS_NEEDED) {
        soft_tree_fallback<<<BATCH / ROWS, 256, 0, stream>>>(x, Wn, bn, Wl, out);
        return;
    }

    f16* xh  = (f16*)((char*)d_ws + XH_OFF);
    f16* wnh = (f16*)((char*)d_ws + WNH_OFF);
    f16* wlt = (f16*)((char*)d_ws + WLT_OFF);
    f16* sp  = (f16*)((char*)d_ws + SP_OFF);

    conv_x_kernel <<<(BATCH * FDIM) / (256 * 4), 256, 0, stream>>>(x, xh);
    conv_wl_kernel<<<64, 256, 0, stream>>>(Wl, wlt);
    conv_wn_kernel<<<dim3(64, FDIM / 64), 256, 0, stream>>>(Wn, wnh);

    gemm_nodes<<<dim3(NJP / 128, BATCH / 128), 256, 0, stream>>>(xh, wnh, bn, sp);
    prob_kernel<<<BATCH / 4, 256, 0, stream>>>(sp);
    leaf_gemm<<<BATCH / 16, 256, 0, stream>>>(sp, wlt, out);
}

// Round 5
// 177.537 us; speedup vs baseline: 12.2996x; 1.0095x over previous
//
#include <hip/hip_runtime.h>
#include <hip/hip_fp16.h>

#define BATCH 8192
#define FDIM  512
#define NTREE 64
#define NODES 63
#define ODIM  128
#define NJ    (NODES*NTREE)   // 4032 real node-tree columns
#define NJP   4096            // padded
#define K2    4096            // leaf GEMM K = 64 leaves * 64 trees

typedef _Float16 f16;
typedef _Float16 f16x8 __attribute__((ext_vector_type(8)));
typedef float    f32x4 __attribute__((ext_vector_type(4)));

// ---------------- workspace layout (bytes) ----------------
#define XH_OFF   0
#define XH_SZ    ((size_t)BATCH*FDIM*2)        // 8.39 MB  x  f16 [b][f]
#define WNH_OFF  (XH_OFF + XH_SZ)
#define WNH_SZ   ((size_t)NJP*FDIM*2)          // 4.19 MB  Wn f16 [j=n*64+t][f], pad j zeroed
#define WLT_OFF  (WNH_OFF + WNH_SZ)
#define WLT_SZ   ((size_t)ODIM*K2*2)           // 1.05 MB  Wl f16 [o][l*64+t]
#define SP_OFF   (WLT_OFF + WLT_SZ)
#define SP_SZ    ((size_t)BATCH*NJP*2)         // 67.1 MB  s f16 [b][j] -> prob in place
#define WS_NEEDED (SP_OFF + SP_SZ)

__device__ __forceinline__ float smooth_step_f(float t) {
    float tc = fminf(fmaxf(t, -0.5f), 0.5f);
    return fmaf(tc, fmaf(-2.0f * tc, tc, 1.5f), 0.5f);
}

__device__ __forceinline__ void async16(const void* g, void* l) {
    __builtin_amdgcn_global_load_lds((__attribute__((address_space(1))) void*)g,
                                     (__attribute__((address_space(3))) void*)l,
                                     16, 0, 0);
}

// swizzled f16 offset of (row, group g) inside a [rows][64] tile staged as
// 1KB chunks of 8 rows; element (r,g) lives at chunk(r>>3), slot (r&7)*8+(g^(r&7))
__device__ __forceinline__ int sw_off(int row, int g) {
    return ((row >> 3) * 512) + (((row & 7) * 8 + (g ^ (row & 7))) * 8);
}

// ---------------- conversions ----------------
__global__ void conv_x_kernel(const float* __restrict__ in, f16* __restrict__ out) {
    size_t i = ((size_t)blockIdx.x * blockDim.x + threadIdx.x) * 4;
    float4 v = *(const float4*)(in + i);
    f16* o = out + i;
    o[0] = (f16)v.x; o[1] = (f16)v.y; o[2] = (f16)v.z; o[3] = (f16)v.w;
}

// Wl[l][o][t] fp32 -> Wlt[o][l*64+t] f16
__global__ void conv_wl_kernel(const float* __restrict__ in, f16* __restrict__ out) {
    const int l  = blockIdx.x;          // 0..63
    const int os = threadIdx.x >> 6;    // 0..3
    const int t  = threadIdx.x & 63;
    for (int oo = 0; oo < 32; ++oo) {
        int o = oo * 4 + os;
        out[(size_t)o * K2 + l * 64 + t] = (f16)in[(size_t)l * (ODIM * NTREE) + o * 64 + t];
    }
}

// Wn[n][f][t] fp32 -> Wnh[(n*64+t)][f] f16 ; block n==63 zeros the pad rows
__global__ void conv_wn_kernel(const float* __restrict__ wn, f16* __restrict__ out) {
    const int n    = blockIdx.x;          // 0..63 (63 = pad)
    const int f0   = blockIdx.y * 64;
    const int lane = threadIdx.x & 63;
    const int w    = threadIdx.x >> 6;
    if (n == NODES) {
        #pragma unroll
        for (int jj = 0; jj < 16; ++jj) {
            int j = NJ + w * 16 + jj;
            out[(size_t)j * FDIM + f0 + lane] = (f16)0.0f;
        }
        return;
    }
    __shared__ float tile[64][65];
    const float* src = wn + (size_t)n * (FDIM * NTREE);
    #pragma unroll
    for (int i = 0; i < 16; ++i) {
        int fl = w * 16 + i;
        tile[fl][lane] = src[(size_t)(f0 + fl) * NTREE + lane];
    }
    __syncthreads();
    #pragma unroll
    for (int i = 0; i < 16; ++i) {
        int tr = w * 16 + i;
        out[(size_t)(n * 64 + tr) * FDIM + f0 + lane] = (f16)tile[lane][tr];
    }
}

// ---------------- phase 1: node GEMM (M=8192, N=4096pad, K=512) + bias + smooth_step ----------------
__global__ __launch_bounds__(256, 3)
void gemm_nodes(const f16* __restrict__ xh, const f16* __restrict__ wnh,
                const float* __restrict__ bn, f16* __restrict__ s_out)
{
    __shared__ f16 SH[128 * 128];         // 32 KB: staging A(16K)+B(16K), then C-tile
    f16* Ash = SH;                        // [128 m][64 k], swizzled chunks
    f16* Bsh = SH + 128 * 64;             // [128 j][64 k], swizzled chunks
    const int tid  = threadIdx.x;
    const int lane = tid & 63;
    const int w    = tid >> 6;
    const int wm   = w & 1;
    const int wn   = w >> 1;
    const int j0   = blockIdx.x * 128;
    const int row0 = blockIdx.y * 128;

    const int lr = lane >> 3;             // row-in-chunk
    const int lg = (lane & 7) ^ lr;       // swizzled group this lane fetches
    f32x4 acc[4][4] = {};

    for (int k0 = 0; k0 < FDIM; k0 += 64) {
        #pragma unroll
        for (int q = 0; q < 8; ++q) {
            int id = w * 8 + q;           // 0..31: 16 A chunks then 16 B chunks
            if (id < 16) {
                int r = id * 8 + lr;
                async16(xh + (size_t)(row0 + r) * FDIM + k0 + lg * 8, &Ash[id * 512 + lane * 8]);
            } else {
                int c = id - 16;
                int r = c * 8 + lr;
                async16(wnh + (size_t)(j0 + r) * FDIM + k0 + lg * 8, &Bsh[c * 512 + lane * 8]);
            }
        }
        __syncthreads();
        #pragma unroll
        for (int ks = 0; ks < 2; ++ks) {
            int g = ks * 4 + (lane >> 4);
            f16x8 bfr[4];
            #pragma unroll
            for (int tn = 0; tn < 4; ++tn) {
                int j = wn * 64 + tn * 16 + (lane & 15);
                bfr[tn] = *(const f16x8*)&Bsh[sw_off(j, g)];
            }
            #pragma unroll
            for (int tm = 0; tm < 4; ++tm) {
                int m = wm * 64 + tm * 16 + (lane & 15);
                f16x8 afr = *(const f16x8*)&Ash[sw_off(m, g)];
                #pragma unroll
                for (int tn = 0; tn < 4; ++tn)
                    acc[tm][tn] = __builtin_amdgcn_mfma_f32_16x16x32_f16(afr, bfr[tn], acc[tm][tn], 0, 0, 0);
            }
        }
        __syncthreads();
    }

    // ---- epilogue: bias+smooth_step into LDS C-tile (swizzled), then coalesced stores ----
    #pragma unroll
    for (int tn = 0; tn < 4; ++tn) {
        int col = wn * 64 + tn * 16 + (lane & 15);
        int j   = j0 + col;
        float bias = (j < NJ) ? bn[j] : 0.0f;   // pad cols: value unused downstream
        #pragma unroll
        for (int tm = 0; tm < 4; ++tm) {
            #pragma unroll
            for (int r = 0; r < 4; ++r) {
                int row = wm * 64 + tm * 16 + (lane >> 4) * 4 + r;
                float v = acc[tm][tn][r] + bias;
                int scol = col ^ (((row >> 2) & 3) << 4);   // bank-spread across quad rows
                SH[row * 128 + scol] = (f16)smooth_step_f(v);
            }
        }
    }
    __syncthreads();
    // 2048 int4 = [128 rows][16 int4]; thread handles 8, consecutive tids -> consecutive int4
    const int4* shv = (const int4*)SH;
    #pragma unroll
    for (int it = 0; it < 8; ++it) {
        int idx = it * 256 + tid;
        int row = idx >> 4, c = idx & 15;
        int src = (row << 4) + (c ^ (((row >> 2) & 3) << 1));  // unswizzle
        ((int4*)(s_out + (size_t)(row0 + row) * NJP + j0))[c] = shv[src];
    }
}

// ---------------- phase 2: prob build, in place, LDS-staged, wave-independent ----------------
__global__ __launch_bounds__(256, 4)
void prob_kernel(f16* sp)
{
    __shared__ f16 stage[4 * 4096];      // 32 KB, one 8 KB row per wave
    const int lane = threadIdx.x & 63;   // tree t
    const int w    = threadIdx.x >> 6;
    const size_t row = (size_t)blockIdx.x * 4 + w;
    f16* rp = sp + row * NJP;
    f16* L  = stage + w * 4096;

    #pragma unroll
    for (int c = 0; c < 8; ++c)
        async16(rp + c * 512 + lane * 8, L + c * 512 + lane * 8);
    __builtin_amdgcn_s_waitcnt(0);       // wave-local drain; rows are wave-private

    float pr[32];
    pr[0] = 1.0f;
    int base = 0;
    #pragma unroll
    for (int lvl = 0; lvl < 5; ++lvl) {
        const int width = 1 << lvl;
        float sl[16];
        #pragma unroll
        for (int i = 0; i < width; ++i)
            sl[i] = (float)L[(base + i) * 64 + lane];
        #pragma unroll
        for (int i = width - 1; i >= 0; --i) {
            float p = pr[i];
            pr[2 * i]     = p * sl[i];
            pr[2 * i + 1] = p * (1.0f - sl[i]);
        }
        base += width;
    }
    // level 5 fold, in place: step i reads gate pos 31+i BEFORE writing leaves 2i, 2i+1.
    #pragma unroll
    for (int i = 0; i < 32; ++i) {
        float s5 = (float)L[(31 + i) * 64 + lane];
        float p  = pr[i];
        L[(2 * i) * 64 + lane]     = (f16)(p * s5);
        L[(2 * i + 1) * 64 + lane] = (f16)(p * (1.0f - s5));
    }
    // vector copy LDS row -> global (overwrites s row incl. pad with prob)
    const int4* ls = (const int4*)L;
    int4* gd = (int4*)rp;
    #pragma unroll
    for (int c = 0; c < 8; ++c)
        gd[c * 64 + lane] = ls[c * 64 + lane];
}

// ---------------- phase 3: leaf GEMM (M=8192, N=128, K=4096), 16 rows/block ----------------
__global__ __launch_bounds__(256, 4)
void leaf_gemm(const f16* __restrict__ prob, const f16* __restrict__ wlt,
               float* __restrict__ out)
{
    __shared__ f16 Ash[2 * 16 * 64];    // 4 KB: 2 k-tiles of [16][64], swizzled
    __shared__ f16 Bsh[2 * 128 * 64];   // 32 KB: 2 k-tiles of [128][64], swizzled
    const int tid  = threadIdx.x;
    const int lane = tid & 63;
    const int w    = tid >> 6;
    const int row0 = blockIdx.x * 16;

    const int lr = lane >> 3;
    const int lg = (lane & 7) ^ lr;
    f32x4 acc[2] = {};

    for (int k0 = 0; k0 < K2; k0 += 128) {
        #pragma unroll
        for (int q = 0; q < 9; ++q) {
            int id = w * 9 + q;            // 0..35: 4 A chunks then 32 B chunks
            if (id < 4) {
                int t = id >> 1, c = id & 1;
                int r = c * 8 + lr;
                async16(prob + (size_t)(row0 + r) * NJP + k0 + t * 64 + lg * 8,
                        &Ash[t * 1024 + c * 512 + lane * 8]);
            } else {
                int e = id - 4;
                int t = e >> 4, c = e & 15;
                int o = c * 8 + lr;
                async16(wlt + (size_t)o * K2 + k0 + t * 64 + lg * 8,
                        &Bsh[t * 8192 + c * 512 + lane * 8]);
            }
        }
        __syncthreads();
        #pragma unroll
        for (int ks = 0; ks < 4; ++ks) {
            int t = ks >> 1;
            int g = (ks & 1) * 4 + (lane >> 4);
            int m = lane & 15;
            f16x8 afr = *(const f16x8*)&Ash[t * 1024 + sw_off(m, g)];
            #pragma unroll
            for (int tn = 0; tn < 2; ++tn) {
                int o = w * 32 + tn * 16 + (lane & 15);
                f16x8 bfr = *(const f16x8*)&Bsh[t * 8192 + sw_off(o, g)];
                acc[tn] = __builtin_amdgcn_mfma_f32_16x16x32_f16(afr, bfr, acc[tn], 0, 0, 0);
            }
        }
        __syncthreads();
    }
    #pragma unroll
    for (int tn = 0; tn < 2; ++tn) {
        int o = w * 32 + tn * 16 + (lane & 15);
        #pragma unroll
        for (int r = 0; r < 4; ++r) {
            int row = row0 + (lane >> 4) * 4 + r;
            out[(size_t)row * ODIM + o] = acc[tn][r];
        }
    }
}

// ---------------- fallback (round-1 proven kernel) ----------------
#define ROWS 8
__global__ __launch_bounds__(256, 2)
void soft_tree_fallback(const float* __restrict__ x, const float* __restrict__ Wn,
                        const float* __restrict__ bn, const float* __restrict__ Wl,
                        float* __restrict__ out)
{
    __shared__ __half s_lds[ROWS][NODES][NTREE];
    const int lane = threadIdx.x & 63;
    const int w    = threadIdx.x >> 6;
    const long row0 = (long)blockIdx.x * ROWS;
    for (int n = w; n < NODES; n += 4) {
        const float* wp = Wn + ((long)n * FDIM) * NTREE + lane;
        const float* xp = x + row0 * FDIM;
        float acc[ROWS];
        #pragma unroll
        for (int r = 0; r < ROWS; ++r) acc[r] = 0.0f;
        #pragma unroll 8
        for (int f = 0; f < FDIM; ++f) {
            float wv = wp[(long)f * NTREE];
            #pragma unroll
            for (int r = 0; r < ROWS; ++r)
                acc[r] = fmaf(xp[r * FDIM + f], wv, acc[r]);
        }
        float bias = bn[n * NTREE + lane];
        #pragma unroll
        for (int r = 0; r < ROWS; ++r)
            s_lds[r][n][lane] = __float2half(smooth_step_f(acc[r] + bias));
    }
    __syncthreads();
    const int r0 = w * 2, r1 = w * 2 + 1;
    float pr0[64], pr1[64];
    {
        pr0[0] = 1.0f; pr1[0] = 1.0f;
        int base = 0;
        #pragma unroll
        for (int lvl = 0; lvl < 6; ++lvl) {
            const int width = 1 << lvl;
            #pragma unroll
            for (int i = width - 1; i >= 0; --i) {
                float sa = __half2float(s_lds[r0][base + i][lane]);
                float sb = __half2float(s_lds[r1][base + i][lane]);
                float pa = pr0[i], pb = pr1[i];
                pr0[2 * i] = pa * sa; pr0[2 * i + 1] = pa * (1.0f - sa);
                pr1[2 * i] = pb * sb; pr1[2 * i + 1] = pb * (1.0f - sb);
            }
            base += width;
        }
    }
    for (int o = 0; o < ODIM; ++o) {
        const float* wlp = Wl + (long)o * NTREE + lane;
        float c0 = 0.0f, c1 = 0.0f;
        #pragma unroll
        for (int l = 0; l < 64; ++l) {
            float wv = wlp[(long)l * (ODIM * NTREE)];
            c0 = fmaf(pr0[l], wv, c0);
            c1 = fmaf(pr1[l], wv, c1);
        }
        #pragma unroll
        for (int off = 32; off > 0; off >>= 1) {
            c0 += __shfl_xor(c0, off, 64);
            c1 += __shfl_xor(c1, off, 64);
        }
        if (lane == 0) {
            out[(row0 + r0) * ODIM + o] = c0;
            out[(row0 + r1) * ODIM + o] = c1;
        }
    }
}

extern "C" void kernel_launch(void* const* d_in, const int* in_sizes, int n_in,
                              void* d_out, int out_size, void* d_ws, size_t ws_size,
                              hipStream_t stream) {
    const float* x  = (const float*)d_in[0];
    const float* Wn = (const float*)d_in[1];
    const float* bn = (const float*)d_in[2];
    const float* Wl = (const float*)d_in[3];
    float* out = (float*)d_out;

    if (ws_size < WS_NEEDED) {
        soft_tree_fallback<<<BATCH / ROWS, 256, 0, stream>>>(x, Wn, bn, Wl, out);
        return;
    }

    f16* xh  = (f16*)((char*)d_ws + XH_OFF);
    f16* wnh = (f16*)((char*)d_ws + WNH_OFF);
    f16* wlt = (f16*)((char*)d_ws + WLT_OFF);
    f16* sp  = (f16*)((char*)d_ws + SP_OFF);

    conv_x_kernel <<<(BATCH * FDIM) / (256 * 4), 256, 0, stream>>>(x, xh);
    conv_wl_kernel<<<64, 256, 0, stream>>>(Wl, wlt);
    conv_wn_kernel<<<dim3(64, FDIM / 64), 256, 0, stream>>>(Wn, wnh);

    gemm_nodes<<<dim3(NJP / 128, BATCH / 128), 256, 0, stream>>>(xh, wnh, bn, sp);
    prob_kernel<<<BATCH / 4, 256, 0, stream>>>(sp);
    leaf_gemm<<<BATCH / 16, 256, 0, stream>>>(sp, wlt, out);
}